// Round 1
// baseline (1181.140 us; speedup 1.0000x reference)
//
#include <hip/hip_runtime.h>
#include <stdint.h>
#include <stddef.h>

#define B_    8192
#define C_    512
#define F_    8
#define COUP_ 1024
#define NBL_  2
#define D1_   256
#define D2_   256

typedef __attribute__((ext_vector_type(8))) short   short8;
typedef __attribute__((ext_vector_type(4))) float   floatx4;

__device__ __forceinline__ unsigned short f2bf(float f) {
  unsigned int u = __float_as_uint(f);
  unsigned int r = (u + 0x7fffu + ((u >> 16) & 1u)) >> 16;
  return (unsigned short)r;
}

__device__ __forceinline__ void gload_lds16(const void* g, void* l) {
  void* gnc = const_cast<void*>(g);
  __builtin_amdgcn_global_load_lds(
      (__attribute__((address_space(1))) void*)gnc,
      (__attribute__((address_space(3))) void*)l, 16, 0, 0);
}

// ---------------------------------------------------------------------------
// GEMM: out[M,N] = A[M,K](bf16) @ W[N,K](bf16)^T  (+bias, epilogue per EPI)
// EPI=0: Wp — write fp32 y into state (ld 512); cols<256 also bf16 -> outB
// EPI=1: relu(acc+bias) -> bf16 outB (ld N)
// EPI=2: 0.1*(acc+bias) -> fp32 outF (ld 512)
// 128x128 tile, 4 waves, 4x4 16x16x32 MFMA per wave, BK=32,
// global_load_lds width=16 staging (m97 structure).
// ---------------------------------------------------------------------------
template<int EPI>
__global__ __launch_bounds__(256, 2)
void gemm_bt(const unsigned short* __restrict__ A,
             const unsigned short* __restrict__ W,
             const float* __restrict__ bias,
             float* __restrict__ outF,
             unsigned short* __restrict__ outB,
             int M, int N, int K)
{
  __shared__ __align__(16) unsigned short lA[128 * 32];
  __shared__ __align__(16) unsigned short lB[128 * 32];
  const int tid  = threadIdx.x;
  const int wave = tid >> 6;
  const int lane = tid & 63;
  const int bm = blockIdx.y * 128;
  const int bn = blockIdx.x * 128;
  const int wm = (wave & 1) * 64;
  const int wn = (wave >> 1) * 64;

  floatx4 acc[4][4];
#pragma unroll
  for (int i = 0; i < 4; ++i)
#pragma unroll
    for (int j = 0; j < 4; ++j)
      acc[i][j] = (floatx4){0.f, 0.f, 0.f, 0.f};

  // staging: per wave 2 insts for A (32 rows) + 2 for B; 64 lanes x 16B = 16 rows/inst
  const int srow  = lane >> 2;
  const int skoff = (lane & 3) * 8;
  const unsigned short* ga = A + (size_t)(bm + wave * 32 + srow) * K + skoff;
  const unsigned short* gb = W + (size_t)(bn + wave * 32 + srow) * K + skoff;
  unsigned short* la0 = &lA[(wave * 32) * 32];
  unsigned short* la1 = &lA[(wave * 32 + 16) * 32];
  unsigned short* lb0 = &lB[(wave * 32) * 32];
  unsigned short* lb1 = &lB[(wave * 32 + 16) * 32];
  const size_t rowstep = (size_t)16 * K;

  const int q8 = (lane >> 4) * 8;  // k-offset of this lane's fragment
  const int r  = lane & 15;        // row/col within 16x16 tile

  for (int k0 = 0; k0 < K; k0 += 32) {
    if (k0) __syncthreads();
    gload_lds16(ga, la0);
    gload_lds16(ga + rowstep, la1);
    gload_lds16(gb, lb0);
    gload_lds16(gb + rowstep, lb1);
    ga += 32; gb += 32;
    __syncthreads();

    short8 af[4], bf[4];
#pragma unroll
    for (int t = 0; t < 4; ++t)
      af[t] = *(const short8*)&lA[(wm + t * 16 + r) * 32 + q8];
#pragma unroll
    for (int t = 0; t < 4; ++t)
      bf[t] = *(const short8*)&lB[(wn + t * 16 + r) * 32 + q8];

#pragma unroll
    for (int i = 0; i < 4; ++i)
#pragma unroll
      for (int j = 0; j < 4; ++j)
        acc[i][j] = __builtin_amdgcn_mfma_f32_16x16x32_bf16(af[i], bf[j], acc[i][j], 0, 0, 0);
  }

  // C/D layout (m89-verified): col = lane&15, row = (lane>>4)*4 + reg
  const int q4 = (lane >> 4) * 4;
  const int cc = lane & 15;
#pragma unroll
  for (int i = 0; i < 4; ++i) {
    const int row0 = bm + wm + i * 16 + q4;
#pragma unroll
    for (int j = 0; j < 4; ++j) {
      const int col = bn + wn + j * 16 + cc;
      float bv = 0.f;
      if (EPI != 0) bv = bias[col];
#pragma unroll
      for (int rr = 0; rr < 4; ++rr) {
        const int row = row0 + rr;
        float v = acc[i][j][rr] + bv;
        if (EPI == 0) {
          outF[(size_t)row * 512 + col] = v;
          if (col < D1_) outB[(size_t)row * D1_ + col] = f2bf(v);
        } else if (EPI == 1) {
          v = v > 0.f ? v : 0.f;
          outB[(size_t)row * N + col] = f2bf(v);
        } else {
          outF[(size_t)row * 512 + col] = 0.1f * v;
        }
      }
    }
  }
}

// scale[f][c] = 0.2*softplus(0.5*g); sumlog[f] = sum_c log(scale)
__global__ void scale_kernel(const float* __restrict__ g, float* __restrict__ sc,
                             float* __restrict__ sumlog) {
  const int f = blockIdx.x, t = threadIdx.x;
  __shared__ float red[256];
  float part = 0.f;
  for (int c = t; c < C_; c += 256) {
    float x  = 0.5f * g[f * C_ + c];
    float sp = log1pf(expf(x));
    float s  = 0.2f * sp;
    sc[f * C_ + c] = s;
    part += logf(s);
  }
  red[t] = part;
  __syncthreads();
  for (int o = 128; o > 0; o >>= 1) {
    if (t < o) red[t] += red[t + o];
    __syncthreads();
  }
  if (t == 0) sumlog[f] = red[0];
}

__global__ void zero_ld_kernel(float* __restrict__ ld) {
  int i = blockIdx.x * blockDim.x + threadIdx.x;
  if (i < B_) ld[i] = 0.f;
}

// fused fp32->bf16 convert of up to 4 regions (one launch per flow block)
__global__ void cvt4_kernel(const float* __restrict__ s0, unsigned short* __restrict__ d0, int n0,
                            const float* __restrict__ s1, unsigned short* __restrict__ d1, int n1,
                            const float* __restrict__ s2, unsigned short* __restrict__ d2, int n2,
                            const float* __restrict__ s3, unsigned short* __restrict__ d3, int n3) {
  const int total4 = (n0 + n1 + n2 + n3) >> 2;
  for (int i = blockIdx.x * blockDim.x + threadIdx.x; i < total4;
       i += gridDim.x * blockDim.x) {
    int idx = i << 2;
    const float* s; unsigned short* d; int off;
    if (idx < n0)                { s = s0; d = d0; off = idx; }
    else if (idx < n0 + n1)      { s = s1; d = d1; off = idx - n0; }
    else if (idx < n0 + n1 + n2) { s = s2; d = d2; off = idx - n0 - n1; }
    else                         { s = s3; d = d3; off = idx - n0 - n1 - n2; }
    float4 v = *(const float4*)(s + off);
    ushort4 o;
    o.x = f2bf(v.x); o.y = f2bf(v.y); o.z = f2bf(v.z); o.w = f2bf(v.w);
    *(ushort4*)(d + off) = o;
  }
}

// xb = bf16(x*scale + off), row-broadcast scale/off (length C_)
__global__ void prewp_kernel(const float* __restrict__ x, const float* __restrict__ sc,
                             const float* __restrict__ off, unsigned short* __restrict__ xb) {
  int i = blockIdx.x * blockDim.x + threadIdx.x;          // float4 group
  if (i >= (B_ * C_) / 4) return;
  int idx = i << 2;
  int c = idx & (C_ - 1);
  float4 v = *(const float4*)(x + idx);
  float4 s = *(const float4*)(sc + c);
  float4 o = *(const float4*)(off + c);
  ushort4 r;
  r.x = f2bf(v.x * s.x + o.x);
  r.y = f2bf(v.y * s.y + o.y);
  r.z = f2bf(v.z * s.z + o.z);
  r.w = f2bf(v.w * s.w + o.w);
  *(ushort4*)(xb + idx) = r;
}

// coupling: s=2*tanh(a[:, :256]), t=a[:,256:], x2 <- x2*exp(s)+t, ld += sum(s)
__global__ __launch_bounds__(256)
void couple_kernel(const float* __restrict__ a, float* __restrict__ xst,
                   float* __restrict__ ld) {
  const int wave = threadIdx.x >> 6, lane = threadIdx.x & 63;
  const int row = blockIdx.x * 4 + wave;
  const float* ar = a + (size_t)row * 512;
  float* xr = xst + (size_t)row * C_ + D1_;
  float ssum = 0.f;
#pragma unroll
  for (int j0 = 0; j0 < D2_; j0 += 64) {
    int j = j0 + lane;
    float s = 2.0f * tanhf(ar[j]);
    float t = ar[D2_ + j];
    xr[j] = xr[j] * expf(s) + t;
    ssum += s;
  }
#pragma unroll
  for (int o = 32; o > 0; o >>= 1) ssum += __shfl_down(ssum, o, 64);
  if (lane == 0) ld[row] += ssum;
}

__global__ void final_kernel(const float* __restrict__ xst, const float* __restrict__ ld,
                             const float* __restrict__ sumlog, float* __restrict__ out) {
  size_t i = (size_t)blockIdx.x * blockDim.x + threadIdx.x;
  const size_t nzk = (size_t)B_ * C_;
  if (i < nzk) {
    out[i] = xst[i];
  } else if (i < nzk + B_) {
    float t = 0.f;
#pragma unroll
    for (int f = 0; f < F_; ++f) t += sumlog[f];
    out[i] = ld[i - nzk] + t;
  }
}

extern "C" void kernel_launch(void* const* d_in, const int* in_sizes, int n_in,
                              void* d_out, int out_size, void* d_ws, size_t ws_size,
                              hipStream_t stream) {
  const float* z0  = (const float*)d_in[0];
  const float* Wp  = (const float*)d_in[1];
  const float* g   = (const float*)d_in[2];
  const float* off = (const float*)d_in[3];
  const float* w0  = (const float*)d_in[4];
  const float* b0  = (const float*)d_in[5];
  const float* wh  = (const float*)d_in[6];
  const float* bh  = (const float*)d_in[7];
  const float* wo  = (const float*)d_in[8];
  const float* bo  = (const float*)d_in[9];
  float* out = (float*)d_out;

  char* ws = (char*)d_ws;
  size_t p = 0;
  auto alloc = [&](size_t bytes) -> void* {
    p = (p + 255) & ~(size_t)255;
    void* r = ws + p;
    p += bytes;
    return r;
  };
  float* sc             = (float*)alloc((size_t)F_ * C_ * 4);
  float* sumlog         = (float*)alloc((size_t)F_ * 4);
  float* ld             = (float*)alloc((size_t)B_ * 4);
  float* xst            = (float*)alloc((size_t)B_ * C_ * 4);
  unsigned short* xb    = (unsigned short*)alloc((size_t)B_ * C_ * 2);
  unsigned short* x1b   = (unsigned short*)alloc((size_t)B_ * D1_ * 2);
  unsigned short* h1b   = (unsigned short*)alloc((size_t)B_ * COUP_ * 2);
  unsigned short* h2b   = (unsigned short*)alloc((size_t)B_ * COUP_ * 2);
  float* abuf           = (float*)h2b;  // alias: wo output (B x 512 fp32) over dead h2 bf16
  unsigned short* wpb   = (unsigned short*)alloc((size_t)C_ * C_ * 2);
  unsigned short* w0b   = (unsigned short*)alloc((size_t)COUP_ * D1_ * 2);
  unsigned short* whb   = (unsigned short*)alloc((size_t)NBL_ * COUP_ * COUP_ * 2);
  unsigned short* wob   = (unsigned short*)alloc((size_t)2 * D2_ * COUP_ * 2);
  (void)ws_size; (void)in_sizes; (void)n_in; (void)out_size;

  scale_kernel<<<F_, 256, 0, stream>>>(g, sc, sumlog);
  zero_ld_kernel<<<B_ / 256, 256, 0, stream>>>(ld);

  for (int f = 0; f < F_; ++f) {
    cvt4_kernel<<<1024, 256, 0, stream>>>(
        Wp + (size_t)f * C_ * C_,            wpb, C_ * C_,
        w0 + (size_t)f * COUP_ * D1_,        w0b, COUP_ * D1_,
        wh + (size_t)f * NBL_ * COUP_ * COUP_, whb, NBL_ * COUP_ * COUP_,
        wo + (size_t)f * 2 * D2_ * COUP_,    wob, 2 * D2_ * COUP_);

    prewp_kernel<<<(B_ * C_ / 4) / 256, 256, 0, stream>>>(
        f == 0 ? z0 : xst, sc + (size_t)f * C_, off + (size_t)f * C_, xb);

    // y = (x*scale+off) @ Wp^T  -> state fp32 + x1 bf16
    gemm_bt<0><<<dim3(512 / 128, B_ / 128), 256, 0, stream>>>(
        xb, wpb, nullptr, xst, x1b, B_, 512, 512);

    // h = relu(x1 @ w0^T + b0)
    gemm_bt<1><<<dim3(COUP_ / 128, B_ / 128), 256, 0, stream>>>(
        x1b, w0b, b0 + (size_t)f * COUP_, nullptr, h1b, B_, COUP_, D1_);

    // h = relu(h @ wh0^T + bh0)
    gemm_bt<1><<<dim3(COUP_ / 128, B_ / 128), 256, 0, stream>>>(
        h1b, whb, bh + (size_t)(f * NBL_ + 0) * COUP_, nullptr, h2b, B_, COUP_, COUP_);

    // h = relu(h @ wh1^T + bh1)
    gemm_bt<1><<<dim3(COUP_ / 128, B_ / 128), 256, 0, stream>>>(
        h2b, whb + (size_t)COUP_ * COUP_, bh + (size_t)(f * NBL_ + 1) * COUP_,
        nullptr, h1b, B_, COUP_, COUP_);

    // a = 0.1*(h @ wo^T + bo) -> abuf fp32 (aliases h2b, already consumed)
    gemm_bt<2><<<dim3(512 / 128, B_ / 128), 256, 0, stream>>>(
        h1b, wob, bo + (size_t)f * 2 * D2_, abuf, nullptr, B_, 512, COUP_);

    couple_kernel<<<B_ / 4, 256, 0, stream>>>(abuf, xst, ld);
  }

  final_kernel<<<(B_ * C_ + B_ + 255) / 256, 256, 0, stream>>>(xst, ld, sumlog, out);
}

// Round 2
// 1138.492 us; speedup vs baseline: 1.0375x; 1.0375x over previous
//
#include <hip/hip_runtime.h>
#include <stdint.h>
#include <stddef.h>

#define B_    8192
#define C_    512
#define F_    8
#define COUP_ 1024
#define NBL_  2
#define D1_   256
#define D2_   256

typedef __attribute__((ext_vector_type(8))) short   short8;
typedef __attribute__((ext_vector_type(4))) float   floatx4;

__device__ __forceinline__ unsigned short f2bf(float f) {
  unsigned int u = __float_as_uint(f);
  unsigned int r = (u + 0x7fffu + ((u >> 16) & 1u)) >> 16;
  return (unsigned short)r;
}

__device__ __forceinline__ void gload_lds16(const void* g, void* l) {
  void* gnc = const_cast<void*>(g);
  __builtin_amdgcn_global_load_lds(
      (__attribute__((address_space(1))) void*)gnc,
      (__attribute__((address_space(3))) void*)l, 16, 0, 0);
}

// ---------------------------------------------------------------------------
// 4-wave GEMM, 128x128 tile (m97 structure): out = A[M,K] @ W[N,K]^T
// EPI=1: relu(acc+bias) -> bf16 outB (ld N).  Used for the three subnet GEMMs
// with grid >= 512 (2 blocks/CU co-resident).
// ---------------------------------------------------------------------------
template<int EPI>
__global__ __launch_bounds__(256, 2)
void gemm_bt(const unsigned short* __restrict__ A,
             const unsigned short* __restrict__ W,
             const float* __restrict__ bias,
             float* __restrict__ outF,
             unsigned short* __restrict__ outB,
             int M, int N, int K)
{
  __shared__ __align__(16) unsigned short lA[128 * 32];
  __shared__ __align__(16) unsigned short lB[128 * 32];
  const int tid  = threadIdx.x;
  const int wave = tid >> 6;
  const int lane = tid & 63;
  const int bm = blockIdx.y * 128;
  const int bn = blockIdx.x * 128;
  const int wm = (wave & 1) * 64;
  const int wn = (wave >> 1) * 64;

  floatx4 acc[4][4];
#pragma unroll
  for (int i = 0; i < 4; ++i)
#pragma unroll
    for (int j = 0; j < 4; ++j)
      acc[i][j] = (floatx4){0.f, 0.f, 0.f, 0.f};

  const int srow  = lane >> 2;
  const int skoff = (lane & 3) * 8;
  const unsigned short* ga = A + (size_t)(bm + wave * 32 + srow) * K + skoff;
  const unsigned short* gb = W + (size_t)(bn + wave * 32 + srow) * K + skoff;
  unsigned short* la0 = &lA[(wave * 32) * 32];
  unsigned short* la1 = &lA[(wave * 32 + 16) * 32];
  unsigned short* lb0 = &lB[(wave * 32) * 32];
  unsigned short* lb1 = &lB[(wave * 32 + 16) * 32];
  const size_t rowstep = (size_t)16 * K;

  const int q8 = (lane >> 4) * 8;
  const int r  = lane & 15;

  for (int k0 = 0; k0 < K; k0 += 32) {
    if (k0) __syncthreads();
    gload_lds16(ga, la0);
    gload_lds16(ga + rowstep, la1);
    gload_lds16(gb, lb0);
    gload_lds16(gb + rowstep, lb1);
    ga += 32; gb += 32;
    __syncthreads();

    short8 af[4], bf[4];
#pragma unroll
    for (int t = 0; t < 4; ++t)
      af[t] = *(const short8*)&lA[(wm + t * 16 + r) * 32 + q8];
#pragma unroll
    for (int t = 0; t < 4; ++t)
      bf[t] = *(const short8*)&lB[(wn + t * 16 + r) * 32 + q8];

#pragma unroll
    for (int i = 0; i < 4; ++i)
#pragma unroll
      for (int j = 0; j < 4; ++j)
        acc[i][j] = __builtin_amdgcn_mfma_f32_16x16x32_bf16(af[i], bf[j], acc[i][j], 0, 0, 0);
  }

  const int q4 = (lane >> 4) * 4;
  const int cc = lane & 15;
#pragma unroll
  for (int i = 0; i < 4; ++i) {
    const int row0 = bm + wm + i * 16 + q4;
#pragma unroll
    for (int j = 0; j < 4; ++j) {
      const int col = bn + wn + j * 16 + cc;
      const float bv = bias[col];
#pragma unroll
      for (int rr = 0; rr < 4; ++rr) {
        const int row = row0 + rr;
        float v = acc[i][j][rr] + bv;
        v = v > 0.f ? v : 0.f;
        outB[(size_t)row * N + col] = f2bf(v);
      }
    }
  }
}

// ---------------------------------------------------------------------------
// 2-wave GEMM, 128x64 tile: for N=512 GEMMs (grid 512 instead of 256).
// Per-wave identical density to m97: 64x64 acc, 16 MFMA : 8 ds_read per BK32.
// EPI=0: Wp epilogue — fp32 y -> outF (ld 512); cols<256 also bf16 -> outB
// EPI=2: wo epilogue — 0.1*(acc+bias) -> fp32 outF (ld 512)
// ---------------------------------------------------------------------------
template<int EPI>
__global__ __launch_bounds__(128, 2)
void gemm_bt64(const unsigned short* __restrict__ A,
               const unsigned short* __restrict__ W,
               const float* __restrict__ bias,
               float* __restrict__ outF,
               unsigned short* __restrict__ outB,
               int M, int N, int K)
{
  __shared__ __align__(16) unsigned short lA[128 * 32];
  __shared__ __align__(16) unsigned short lB[64 * 32];
  const int tid  = threadIdx.x;
  const int wave = tid >> 6;
  const int lane = tid & 63;
  const int bm = blockIdx.y * 128;
  const int bn = blockIdx.x * 64;
  const int wm = wave * 64;

  floatx4 acc[4][4];
#pragma unroll
  for (int i = 0; i < 4; ++i)
#pragma unroll
    for (int j = 0; j < 4; ++j)
      acc[i][j] = (floatx4){0.f, 0.f, 0.f, 0.f};

  const int srow  = lane >> 2;
  const int skoff = (lane & 3) * 8;
  // per wave: 4 insts for its 64 A-rows, 2 insts for its 32 B-rows
  const unsigned short* ga = A + (size_t)(bm + wave * 64 + srow) * K + skoff;
  const unsigned short* gb = W + (size_t)(bn + wave * 32 + srow) * K + skoff;
  unsigned short* laB = &lA[(wave * 64) * 32];
  unsigned short* lbB = &lB[(wave * 32) * 32];
  const size_t rowstep = (size_t)16 * K;

  const int q8 = (lane >> 4) * 8;
  const int r  = lane & 15;

  for (int k0 = 0; k0 < K; k0 += 32) {
    if (k0) __syncthreads();
    gload_lds16(ga,               laB);
    gload_lds16(ga + rowstep,     laB + 16 * 32);
    gload_lds16(ga + 2 * rowstep, laB + 32 * 32);
    gload_lds16(ga + 3 * rowstep, laB + 48 * 32);
    gload_lds16(gb,               lbB);
    gload_lds16(gb + rowstep,     lbB + 16 * 32);
    ga += 32; gb += 32;
    __syncthreads();

    short8 af[4], bf[4];
#pragma unroll
    for (int t = 0; t < 4; ++t)
      af[t] = *(const short8*)&lA[(wm + t * 16 + r) * 32 + q8];
#pragma unroll
    for (int t = 0; t < 4; ++t)
      bf[t] = *(const short8*)&lB[(t * 16 + r) * 32 + q8];

#pragma unroll
    for (int i = 0; i < 4; ++i)
#pragma unroll
      for (int j = 0; j < 4; ++j)
        acc[i][j] = __builtin_amdgcn_mfma_f32_16x16x32_bf16(af[i], bf[j], acc[i][j], 0, 0, 0);
  }

  const int q4 = (lane >> 4) * 4;
  const int cc = lane & 15;
#pragma unroll
  for (int i = 0; i < 4; ++i) {
    const int row0 = bm + wm + i * 16 + q4;
#pragma unroll
    for (int j = 0; j < 4; ++j) {
      const int col = bn + j * 16 + cc;
      float bv = 0.f;
      if (EPI != 0) bv = bias[col];
#pragma unroll
      for (int rr = 0; rr < 4; ++rr) {
        const int row = row0 + rr;
        float v = acc[i][j][rr] + bv;
        if (EPI == 0) {
          outF[(size_t)row * 512 + col] = v;
          if (col < D1_) outB[(size_t)row * D1_ + col] = f2bf(v);
        } else {
          outF[(size_t)row * 512 + col] = 0.1f * v;
        }
      }
    }
  }
}

// scale[f][c] = 0.2*softplus(0.5*g); sumlog[f] = sum_c log(scale)
__global__ void scale_kernel(const float* __restrict__ g, float* __restrict__ sc,
                             float* __restrict__ sumlog) {
  const int f = blockIdx.x, t = threadIdx.x;
  __shared__ float red[256];
  float part = 0.f;
  for (int c = t; c < C_; c += 256) {
    float x  = 0.5f * g[f * C_ + c];
    float sp = log1pf(expf(x));
    float s  = 0.2f * sp;
    sc[f * C_ + c] = s;
    part += logf(s);
  }
  red[t] = part;
  __syncthreads();
  for (int o = 128; o > 0; o >>= 1) {
    if (t < o) red[t] += red[t + o];
    __syncthreads();
  }
  if (t == 0) sumlog[f] = red[0];
}

// one-shot fp32->bf16 convert of all weights (each region contiguous over f)
__global__ void cvt4_kernel(const float* __restrict__ s0, unsigned short* __restrict__ d0, int n0,
                            const float* __restrict__ s1, unsigned short* __restrict__ d1, int n1,
                            const float* __restrict__ s2, unsigned short* __restrict__ d2, int n2,
                            const float* __restrict__ s3, unsigned short* __restrict__ d3, int n3) {
  const int total4 = (n0 + n1 + n2 + n3) >> 2;
  for (int i = blockIdx.x * blockDim.x + threadIdx.x; i < total4;
       i += gridDim.x * blockDim.x) {
    int idx = i << 2;
    const float* s; unsigned short* d; int off;
    if (idx < n0)                { s = s0; d = d0; off = idx; }
    else if (idx < n0 + n1)      { s = s1; d = d1; off = idx - n0; }
    else if (idx < n0 + n1 + n2) { s = s2; d = d2; off = idx - n0 - n1; }
    else                         { s = s3; d = d3; off = idx - n0 - n1 - n2; }
    float4 v = *(const float4*)(s + off);
    ushort4 o;
    o.x = f2bf(v.x); o.y = f2bf(v.y); o.z = f2bf(v.z); o.w = f2bf(v.w);
    *(ushort4*)(d + off) = o;
  }
}

// f=0 only: xb = bf16(z0*scale + off); also zero ld
__global__ void prewp_kernel(const float* __restrict__ x, const float* __restrict__ sc,
                             const float* __restrict__ off, unsigned short* __restrict__ xb,
                             float* __restrict__ ld) {
  int i = blockIdx.x * blockDim.x + threadIdx.x;
  if (i < B_ / 4) *(float4*)(ld + i * 4) = (float4){0.f, 0.f, 0.f, 0.f};
  if (i >= (B_ * C_) / 4) return;
  int idx = i << 2;
  int c = idx & (C_ - 1);
  float4 v = *(const float4*)(x + idx);
  float4 s = *(const float4*)(sc + c);
  float4 o = *(const float4*)(off + c);
  ushort4 r;
  r.x = f2bf(v.x * s.x + o.x);
  r.y = f2bf(v.y * s.y + o.y);
  r.z = f2bf(v.z * s.z + o.z);
  r.w = f2bf(v.w * s.w + o.w);
  *(ushort4*)(xb + idx) = r;
}

// coupling + fused next-block prewp:
//   s=2*tanh(a[:, :256]), t=a[:,256:], x2 <- x2*exp(s)+t, ld += sum(s)
//   if !LAST: xb = bf16(x_new * sc_next + off_next) for full row (512)
template<int LAST>
__global__ __launch_bounds__(256)
void couple_kernel(const float* __restrict__ a, float* __restrict__ xst,
                   float* __restrict__ ld,
                   const float* __restrict__ scn, const float* __restrict__ offn,
                   unsigned short* __restrict__ xb) {
  const int wave = threadIdx.x >> 6, lane = threadIdx.x & 63;
  const int row = blockIdx.x * 4 + wave;
  const float* ar = a + (size_t)row * 512;
  float* xr = xst + (size_t)row * C_;
  float nx2[4];
  float ssum = 0.f;
#pragma unroll
  for (int it = 0; it < 4; ++it) {
    int j = it * 64 + lane;
    float s = 2.0f * tanhf(ar[j]);
    float t = ar[D2_ + j];
    float v = xr[D1_ + j] * expf(s) + t;
    xr[D1_ + j] = v;
    nx2[it] = v;
    ssum += s;
  }
#pragma unroll
  for (int o = 32; o > 0; o >>= 1) ssum += __shfl_down(ssum, o, 64);
  if (lane == 0) ld[row] += ssum;

  if (!LAST) {
    unsigned short* xbr = xb + (size_t)row * C_;
#pragma unroll
    for (int it = 0; it < 4; ++it) {
      int c = it * 64 + lane;
      xbr[c] = f2bf(xr[c] * scn[c] + offn[c]);
    }
#pragma unroll
    for (int it = 0; it < 4; ++it) {
      int c = D1_ + it * 64 + lane;
      xbr[c] = f2bf(nx2[it] * scn[c] + offn[c]);
    }
  }
}

__global__ void final_kernel(const float* __restrict__ xst, const float* __restrict__ ld,
                             const float* __restrict__ sumlog, float* __restrict__ out) {
  size_t i = (size_t)blockIdx.x * blockDim.x + threadIdx.x;
  const size_t nzk = (size_t)B_ * C_;
  if (i < nzk) {
    out[i] = xst[i];
  } else if (i < nzk + B_) {
    float t = 0.f;
#pragma unroll
    for (int f = 0; f < F_; ++f) t += sumlog[f];
    out[i] = ld[i - nzk] + t;
  }
}

extern "C" void kernel_launch(void* const* d_in, const int* in_sizes, int n_in,
                              void* d_out, int out_size, void* d_ws, size_t ws_size,
                              hipStream_t stream) {
  const float* z0  = (const float*)d_in[0];
  const float* Wp  = (const float*)d_in[1];
  const float* g   = (const float*)d_in[2];
  const float* off = (const float*)d_in[3];
  const float* w0  = (const float*)d_in[4];
  const float* b0  = (const float*)d_in[5];
  const float* wh  = (const float*)d_in[6];
  const float* bh  = (const float*)d_in[7];
  const float* wo  = (const float*)d_in[8];
  const float* bo  = (const float*)d_in[9];
  float* out = (float*)d_out;

  char* ws = (char*)d_ws;
  size_t p = 0;
  auto alloc = [&](size_t bytes) -> void* {
    p = (p + 255) & ~(size_t)255;
    void* r = ws + p;
    p += bytes;
    return r;
  };
  float* sc             = (float*)alloc((size_t)F_ * C_ * 4);
  float* sumlog         = (float*)alloc((size_t)F_ * 4);
  float* ld             = (float*)alloc((size_t)B_ * 4);
  float* xst            = (float*)alloc((size_t)B_ * C_ * 4);
  unsigned short* xb    = (unsigned short*)alloc((size_t)B_ * C_ * 2);
  unsigned short* x1b   = (unsigned short*)alloc((size_t)B_ * D1_ * 2);
  unsigned short* h1b   = (unsigned short*)alloc((size_t)B_ * COUP_ * 2);
  unsigned short* h2b   = (unsigned short*)alloc((size_t)B_ * COUP_ * 2);
  float* abuf           = (float*)h2b;  // alias: wo output (B x 512 fp32) over dead h2 bf16
  // all-blocks bf16 weights (converted once up front)
  unsigned short* wpb   = (unsigned short*)alloc((size_t)F_ * C_ * C_ * 2);
  unsigned short* w0b   = (unsigned short*)alloc((size_t)F_ * COUP_ * D1_ * 2);
  unsigned short* whb   = (unsigned short*)alloc((size_t)F_ * NBL_ * COUP_ * COUP_ * 2);
  unsigned short* wob   = (unsigned short*)alloc((size_t)F_ * 2 * D2_ * COUP_ * 2);
  (void)ws_size; (void)in_sizes; (void)n_in; (void)out_size;

  scale_kernel<<<F_, 256, 0, stream>>>(g, sc, sumlog);

  // one-shot weight conversion for all 8 blocks (each tensor contiguous over f)
  cvt4_kernel<<<4096, 256, 0, stream>>>(
      Wp, wpb, F_ * C_ * C_,
      w0, w0b, F_ * COUP_ * D1_,
      wh, whb, F_ * NBL_ * COUP_ * COUP_,
      wo, wob, F_ * 2 * D2_ * COUP_);

  // f=0 affine+cast (+ld zero); later blocks get this fused into couple_kernel
  prewp_kernel<<<(B_ * C_ / 4) / 256, 256, 0, stream>>>(z0, sc, off, xb, ld);

  for (int f = 0; f < F_; ++f) {
    // y = (x*scale+off) @ Wp^T  -> state fp32 + x1 bf16   [2-wave, grid 512]
    gemm_bt64<0><<<dim3(512 / 64, B_ / 128), 128, 0, stream>>>(
        xb, wpb + (size_t)f * C_ * C_, nullptr, xst, x1b, B_, 512, 512);

    // h = relu(x1 @ w0^T + b0)                            [4-wave, grid 512]
    gemm_bt<1><<<dim3(COUP_ / 128, B_ / 128), 256, 0, stream>>>(
        x1b, w0b + (size_t)f * COUP_ * D1_, b0 + (size_t)f * COUP_,
        nullptr, h1b, B_, COUP_, D1_);

    // h = relu(h @ wh0^T + bh0)
    gemm_bt<1><<<dim3(COUP_ / 128, B_ / 128), 256, 0, stream>>>(
        h1b, whb + (size_t)(f * NBL_) * COUP_ * COUP_,
        bh + (size_t)(f * NBL_ + 0) * COUP_, nullptr, h2b, B_, COUP_, COUP_);

    // h = relu(h @ wh1^T + bh1)
    gemm_bt<1><<<dim3(COUP_ / 128, B_ / 128), 256, 0, stream>>>(
        h2b, whb + (size_t)(f * NBL_ + 1) * COUP_ * COUP_,
        bh + (size_t)(f * NBL_ + 1) * COUP_, nullptr, h1b, B_, COUP_, COUP_);

    // a = 0.1*(h @ wo^T + bo) -> abuf fp32 (aliases dead h2b)  [2-wave, grid 512]
    gemm_bt64<2><<<dim3(512 / 64, B_ / 128), 128, 0, stream>>>(
        h1b, wob + (size_t)f * 2 * D2_ * COUP_, bo + (size_t)f * 2 * D2_,
        abuf, nullptr, B_, 512, COUP_);

    // coupling update (+ fused next-block affine+cast for f<7)
    if (f < F_ - 1) {
      couple_kernel<0><<<B_ / 4, 256, 0, stream>>>(
          abuf, xst, ld, sc + (size_t)(f + 1) * C_, off + (size_t)(f + 1) * C_, xb);
    } else {
      couple_kernel<1><<<B_ / 4, 256, 0, stream>>>(
          abuf, xst, ld, nullptr, nullptr, nullptr);
    }
  }

  final_kernel<<<(B_ * C_ + B_ + 255) / 256, 256, 0, stream>>>(xst, ld, sumlog, out);
}